// Round 1
// baseline (3898.181 us; speedup 1.0000x reference)
//
#include <hip/hip_runtime.h>
#include <math.h>

#define HIDN  2048
#define NH    16
#define DNOPE 128
#define DROPE 64
#define DQ    192
#define DV    128
#define QRANK 1536
#define KVRANK 512
#define SEQ   1024
#define NBATCH 2
#define NTOK  (NBATCH*SEQ)
#define EPSV  1e-6f

// ---------------------------------------------------------------------------
// GEMM: C = X[N x K] @ W[M x K]^T.  Tile 64x64, BK=32, 256 threads, 4x4 micro.
// STORE_MODE 0: C[n*M + m]
// STORE_MODE 1: head-major: h=m/Dh, d=m%Dh, b=n/SEQ, s=n%SEQ
//               C[((b*(M/Dh)+h)*SEQ+s)*Dh + d]
// ---------------------------------------------------------------------------
template<int STORE_MODE>
__global__ __launch_bounds__(256)
void gemm_xwt(const float* __restrict__ X, const float* __restrict__ W,
              float* __restrict__ C, int K, int M, int Dh)
{
    __shared__ __align__(16) float As[32][68];
    __shared__ __align__(16) float Bs[32][68];
    const int tid = threadIdx.x;
    const int bn = blockIdx.x * 64;   // feature offset
    const int bm = blockIdx.y * 64;   // token offset
    const int tx = tid & 15, ty = tid >> 4;
    float acc[4][4] = {};

    for (int k0 = 0; k0 < K; k0 += 32) {
        #pragma unroll
        for (int i = 0; i < 2; i++) {
            int idx = tid + i * 256;       // 0..511 float4 slots
            int r = idx >> 3;              // row in tile (0..63)
            int kq = idx & 7;              // float4 within 32-k
            float4 xv = *(const float4*)(&X[(size_t)(bm + r) * K + k0 + kq * 4]);
            As[kq*4+0][r] = xv.x; As[kq*4+1][r] = xv.y;
            As[kq*4+2][r] = xv.z; As[kq*4+3][r] = xv.w;
            float4 wv = *(const float4*)(&W[(size_t)(bn + r) * K + k0 + kq * 4]);
            Bs[kq*4+0][r] = wv.x; Bs[kq*4+1][r] = wv.y;
            Bs[kq*4+2][r] = wv.z; Bs[kq*4+3][r] = wv.w;
        }
        __syncthreads();
        #pragma unroll
        for (int kk = 0; kk < 32; kk++) {
            float4 a4 = *(const float4*)(&As[kk][ty * 4]);
            float4 b4 = *(const float4*)(&Bs[kk][tx * 4]);
            float a[4] = {a4.x, a4.y, a4.z, a4.w};
            float b[4] = {b4.x, b4.y, b4.z, b4.w};
            #pragma unroll
            for (int i = 0; i < 4; i++)
                #pragma unroll
                for (int j = 0; j < 4; j++)
                    acc[i][j] += a[i] * b[j];
        }
        __syncthreads();
    }

    #pragma unroll
    for (int i = 0; i < 4; i++) {
        int n = bm + ty * 4 + i;
        #pragma unroll
        for (int j = 0; j < 4; j++) {
            int m = bn + tx * 4 + j;
            size_t addr;
            if (STORE_MODE == 0) {
                addr = (size_t)n * M + m;
            } else {
                int h = m / Dh, d = m - h * Dh;
                int b = n / SEQ, s = n - b * SEQ;
                int Hn = M / Dh;
                addr = ((size_t)((b * Hn + h) * SEQ + s)) * Dh + d;
            }
            C[addr] = acc[i][j];
        }
    }
}

// ---------------------------------------------------------------------------
// Row-wise RMSNorm: out = x * rsqrt(mean(x^2)+eps) * w.  One block per row.
// ---------------------------------------------------------------------------
__global__ __launch_bounds__(256)
void rmsnorm_k(const float* __restrict__ in, int in_stride,
               float* __restrict__ out, int out_stride,
               const float* __restrict__ w, int D)
{
    const int row = blockIdx.x;
    const float* x = in + (size_t)row * in_stride;
    float* y = out + (size_t)row * out_stride;
    float ss = 0.f;
    for (int d = threadIdx.x; d < D; d += 256) { float v = x[d]; ss += v * v; }
    __shared__ float red[256];
    red[threadIdx.x] = ss;
    __syncthreads();
    for (int off = 128; off > 0; off >>= 1) {
        if (threadIdx.x < off) red[threadIdx.x] += red[threadIdx.x + off];
        __syncthreads();
    }
    float inv = rsqrtf(red[0] / (float)D + EPSV);
    for (int d = threadIdx.x; d < D; d += 256) y[d] = x[d] * inv * w[d];
}

// ---------------------------------------------------------------------------
// RoPE on qf (in place). qf layout [b,h,s,DQ]; rope applies to last 64 dims.
// One thread per (bh, s, pair i<32).
// ---------------------------------------------------------------------------
__global__ __launch_bounds__(256)
void rope_q_k(float* __restrict__ qf)
{
    int t = blockIdx.x * 256 + threadIdx.x;       // B*H*S*32 threads
    int i  = t & 31;
    int s  = (t >> 5) & (SEQ - 1);
    int bh = t >> 15;                              // S*32 = 2^15 per bh
    float inv_freq = powf(10000.f, -(float)i / 32.f);
    float ang = (float)s * inv_freq;
    float c = cosf(ang), sn = sinf(ang);
    float* p = qf + ((size_t)bh * SEQ + s) * DQ;
    float x1 = p[DNOPE + i], x2 = p[DNOPE + 32 + i];
    p[DNOPE + i]      = x1 * c - x2 * sn;
    p[DNOPE + 32 + i] = x2 * c + x1 * sn;
}

// kf[b,h,s,0:128] = kvbuf[b,h,s,0:128] (k_nope part of [b,h,s,256])
__global__ __launch_bounds__(256)
void copy_knope_k(const float* __restrict__ kvbuf, float* __restrict__ kf)
{
    int t = blockIdx.x * 256 + threadIdx.x;       // B*H*S*128 threads
    int d  = t & 127;
    int s  = (t >> 7) & (SEQ - 1);
    int bh = t >> 17;                              // S*128 = 2^17 per bh
    kf[((size_t)bh * SEQ + s) * DQ + d] = kvbuf[((size_t)bh * SEQ + s) * 256 + d];
}

// kf[b,h,s,128:192] = rope(k_pe) from kv_a[b,s,512 + h*64 + j]
__global__ __launch_bounds__(256)
void rope_k_k(const float* __restrict__ kva, float* __restrict__ kf)
{
    int t = blockIdx.x * 256 + threadIdx.x;       // B*H*S*32 threads
    int i  = t & 31;
    int s  = (t >> 5) & (SEQ - 1);
    int bh = t >> 15;
    int h = bh & (NH - 1), b = bh >> 4;
    float inv_freq = powf(10000.f, -(float)i / 32.f);
    float ang = (float)s * inv_freq;
    float c = cosf(ang), sn = sinf(ang);
    const float* src = kva + ((size_t)(b * SEQ + s)) * 1536 + KVRANK + h * DROPE;
    float x1 = src[i], x2 = src[32 + i];
    float* dst = kf + ((size_t)bh * SEQ + s) * DQ + DNOPE;
    dst[i]      = x1 * c - x2 * sn;
    dst[32 + i] = x2 * c + x1 * sn;
}

// ---------------------------------------------------------------------------
// Flash attention (fp32). Q,K layout [b,h,s,DQK] contiguous; V strided rows.
// Output ctx token-major: ctx[((b*SEQ+s)*NH+h)*128 + d].
// Block: 256 threads, 32 q-rows x full S loop in 32-key tiles.
// ---------------------------------------------------------------------------
template<int DQK>
__global__ __launch_bounds__(256)
void flash_attn(const float* __restrict__ Q, const float* __restrict__ Kf,
                const float* __restrict__ V, int vstride,
                float* __restrict__ ctx_out, float scale)
{
    constexpr int PAD = DQK + 1;   // stride ≡ 1 mod 32 → conflict-free
    __shared__ float qs[32][PAD];
    __shared__ float ks[32][PAD];  // reused as V tile (cols 0..127)
    __shared__ float ps[32][33];
    __shared__ float rmax[32], rsum[32], ralpha[32];

    const int tid = threadIdx.x;
    const int qt = blockIdx.x;
    const int h = blockIdx.y, b = blockIdx.z;
    const size_t bh = (size_t)b * NH + h;
    const float* Qb = Q + (bh * SEQ + (size_t)qt * 32) * DQK;
    const float* Kb = Kf + bh * SEQ * (size_t)DQK;
    const float* Vb = V + bh * SEQ * (size_t)vstride;

    for (int idx = tid; idx < 32 * DQK; idx += 256) {
        int r = idx / DQK, d = idx % DQK;
        qs[r][d] = Qb[(size_t)r * DQK + d];
    }
    if (tid < 32) { rmax[tid] = -INFINITY; rsum[tid] = 0.f; }

    const int rp = tid >> 4;    // 0..15 row pair (score phase)
    const int cp = tid & 15;    // 0..15 col pair
    const int orow = tid >> 3;  // 0..31 (PV phase)
    const int og = tid & 7;     // dim group: d = 8k + og
    float o[16];
    #pragma unroll
    for (int k = 0; k < 16; k++) o[k] = 0.f;
    __syncthreads();

    for (int kt = 0; kt < SEQ / 32; kt++) {
        for (int idx = tid; idx < 32 * DQK; idx += 256) {   // A: K tile
            int r = idx / DQK, d = idx % DQK;
            ks[r][d] = Kb[((size_t)(kt * 32 + r)) * DQK + d];
        }
        __syncthreads();                                    // S1
        float s00 = 0, s01 = 0, s10 = 0, s11 = 0;           // B: scores 2x2
        #pragma unroll 4
        for (int d = 0; d < DQK; d++) {
            float q0 = qs[2*rp][d],   q1 = qs[2*rp+1][d];
            float k0 = ks[2*cp][d],   k1 = ks[2*cp+1][d];
            s00 += q0 * k0; s01 += q0 * k1;
            s10 += q1 * k0; s11 += q1 * k1;
        }
        __syncthreads();                                    // S2
        ps[2*rp  ][2*cp] = s00 * scale; ps[2*rp  ][2*cp+1] = s01 * scale;
        ps[2*rp+1][2*cp] = s10 * scale; ps[2*rp+1][2*cp+1] = s11 * scale;
        for (int idx = tid; idx < 32 * 128; idx += 256) {   // C: V tile
            int r = idx >> 7, d = idx & 127;
            ks[r][d] = Vb[((size_t)(kt * 32 + r)) * vstride + d];
        }
        __syncthreads();                                    // S3
        if (tid < 32) {                                     // D: online softmax
            int r = tid;
            float mold = rmax[r];
            float mt = mold;
            #pragma unroll
            for (int n = 0; n < 32; n++) mt = fmaxf(mt, ps[r][n]);
            float a = __expf(mold - mt);
            float sum = 0.f;
            #pragma unroll
            for (int n = 0; n < 32; n++) {
                float e = __expf(ps[r][n] - mt);
                ps[r][n] = e; sum += e;
            }
            rsum[r] = rsum[r] * a + sum;
            rmax[r] = mt;
            ralpha[r] = a;
        }
        __syncthreads();                                    // S4
        float a = ralpha[orow];                             // E: PV
        #pragma unroll
        for (int k = 0; k < 16; k++) o[k] *= a;
        for (int n = 0; n < 32; n++) {
            float p = ps[orow][n];
            #pragma unroll
            for (int k = 0; k < 16; k++) o[k] += p * ks[n][8 * k + og];
        }
        __syncthreads();                                    // S5
    }
    float inv = 1.f / rsum[orow];
    int s = qt * 32 + orow;
    float* dst = ctx_out + ((size_t)(b * SEQ + s) * NH + h) * DV;
    #pragma unroll
    for (int k = 0; k < 16; k++) dst[8 * k + og] = o[k] * inv;
}

// ---------------------------------------------------------------------------
// Gate + combine: out = g0*main + g1*pattern, g = softmax(x@gate_w^T + b).
// One block per token.
// ---------------------------------------------------------------------------
__global__ __launch_bounds__(256)
void gate_combine(const float* __restrict__ x, const float* __restrict__ gw,
                  const float* __restrict__ gb,
                  const float* __restrict__ mo, const float* __restrict__ po,
                  float* __restrict__ out)
{
    const int tok = blockIdx.x;
    const float* xr = x + (size_t)tok * HIDN;
    float d0 = 0.f, d1 = 0.f;
    for (int i = threadIdx.x; i < HIDN; i += 256) {
        float v = xr[i];
        d0 += v * gw[i];
        d1 += v * gw[HIDN + i];
    }
    __shared__ float r0[256], r1[256];
    r0[threadIdx.x] = d0; r1[threadIdx.x] = d1;
    __syncthreads();
    for (int off = 128; off > 0; off >>= 1) {
        if (threadIdx.x < off) {
            r0[threadIdx.x] += r0[threadIdx.x + off];
            r1[threadIdx.x] += r1[threadIdx.x + off];
        }
        __syncthreads();
    }
    float l0 = r0[0] + gb[0], l1 = r1[0] + gb[1];
    float m = fmaxf(l0, l1);
    float e0 = __expf(l0 - m), e1 = __expf(l1 - m);
    float g0 = e0 / (e0 + e1), g1 = e1 / (e0 + e1);
    const float* mr = mo + (size_t)tok * HIDN;
    const float* pr = po + (size_t)tok * HIDN;
    float* orow = out + (size_t)tok * HIDN;
    for (int i = threadIdx.x; i < HIDN; i += 256)
        orow[i] = g0 * mr[i] + g1 * pr[i];
}

// ---------------------------------------------------------------------------
extern "C" void kernel_launch(void* const* d_in, const int* in_sizes, int n_in,
                              void* d_out, int out_size, void* d_ws, size_t ws_size,
                              hipStream_t stream)
{
    const float* X        = (const float*)d_in[0];
    const float* q_a_w    = (const float*)d_in[1];
    const float* q_a_ln_w = (const float*)d_in[2];
    const float* q_b_w    = (const float*)d_in[3];
    const float* kv_a_w   = (const float*)d_in[4];
    const float* kv_a_ln_w= (const float*)d_in[5];
    const float* kv_b_w   = (const float*)d_in[6];
    const float* o_w      = (const float*)d_in[7];
    const float* sp_q_w   = (const float*)d_in[8];
    const float* sp_k_w   = (const float*)d_in[9];
    const float* sp_v_w   = (const float*)d_in[10];
    const float* sp_o_w   = (const float*)d_in[11];
    const float* gate_w   = (const float*)d_in[12];
    const float* gate_b   = (const float*)d_in[13];
    float* out = (float*)d_out;

    float* ws = (float*)d_ws;
    // workspace layout (floats)
    float* q_mid   = ws;                       // 2048*1536
    float* kv_a    = ws + 3145728;             // 2048*1536
    float* kv_ln   = ws + 6291456;             // 2048*512
    float* kvbuf   = ws + 7340032;             // [b,h,s,256] 2048*4096
    float* qf      = ws + 15728640;            // [b,h,s,192] 2048*3072
    float* kf      = ws + 22020096;            // [b,h,s,192] 2048*3072
    float* ctx     = ws + 28311552;            // [b,s,h,128] 2048*2048
    float* mainout = ws + 32505856;            // 2048*2048
    float* patout  = ws + 36700160;            // 2048*2048
    // aliases (lifetimes disjoint)
    float* pq    = qf;
    float* pk    = kf;
    float* pv    = kvbuf;
    float* p_ctx = ctx;

    dim3 blk(256);

    // main branch projections
    gemm_xwt<0><<<dim3(QRANK/64, NTOK/64), blk, 0, stream>>>(X, q_a_w, q_mid, HIDN, QRANK, 0);
    rmsnorm_k<<<dim3(NTOK), blk, 0, stream>>>(q_mid, QRANK, q_mid, QRANK, q_a_ln_w, QRANK);
    gemm_xwt<1><<<dim3(NH*DQ/64, NTOK/64), blk, 0, stream>>>(q_mid, q_b_w, qf, QRANK, NH*DQ, DQ);
    gemm_xwt<0><<<dim3(1536/64, NTOK/64), blk, 0, stream>>>(X, kv_a_w, kv_a, HIDN, 1536, 0);
    rmsnorm_k<<<dim3(NTOK), blk, 0, stream>>>(kv_a, 1536, kv_ln, KVRANK, kv_a_ln_w, KVRANK);
    gemm_xwt<1><<<dim3(NH*256/64, NTOK/64), blk, 0, stream>>>(kv_ln, kv_b_w, kvbuf, KVRANK, NH*256, 256);

    // rope + kf pack
    rope_q_k<<<dim3(NBATCH*NH*SEQ*32/256), blk, 0, stream>>>(qf);
    copy_knope_k<<<dim3(NBATCH*NH*SEQ*128/256), blk, 0, stream>>>(kvbuf, kf);
    rope_k_k<<<dim3(NBATCH*NH*SEQ*32/256), blk, 0, stream>>>(kv_a, kf);

    // main attention
    float scale_main = 1.0f / sqrtf((float)DQ);
    flash_attn<DQ><<<dim3(SEQ/32, NH, NBATCH), blk, 0, stream>>>(
        qf, kf, kvbuf + DNOPE, 256, ctx, scale_main);
    gemm_xwt<0><<<dim3(HIDN/64, NTOK/64), blk, 0, stream>>>(ctx, o_w, mainout, HIDN, HIDN, 0);

    // pattern branch
    gemm_xwt<1><<<dim3(HIDN/64, NTOK/64), blk, 0, stream>>>(X, sp_q_w, pq, HIDN, HIDN, 128);
    gemm_xwt<1><<<dim3(HIDN/64, NTOK/64), blk, 0, stream>>>(X, sp_k_w, pk, HIDN, HIDN, 128);
    gemm_xwt<1><<<dim3(HIDN/64, NTOK/64), blk, 0, stream>>>(X, sp_v_w, pv, HIDN, HIDN, 128);
    float scale_pat = 1.0f / sqrtf(128.0f);
    flash_attn<128><<<dim3(SEQ/32, NH, NBATCH), blk, 0, stream>>>(
        pq, pk, pv, 128, p_ctx, scale_pat);
    gemm_xwt<0><<<dim3(HIDN/64, NTOK/64), blk, 0, stream>>>(p_ctx, sp_o_w, patout, HIDN, HIDN, 0);

    // gate + combine
    gate_combine<<<dim3(NTOK), blk, 0, stream>>>(X, gate_w, gate_b, mainout, patout, out);
}

// Round 2
// 825.380 us; speedup vs baseline: 4.7229x; 4.7229x over previous
//
#include <hip/hip_runtime.h>
#include <math.h>
#include <stdint.h>

#define HIDN  2048
#define NH    16
#define DNOPE 128
#define DROPE 64
#define DQ    192
#define DV    128
#define QRANK 1536
#define KVRANK 512
#define SEQ   1024
#define NBATCH 2
#define NTOK  (NBATCH*SEQ)
#define EPSV  1e-6f

typedef unsigned short u16;
typedef unsigned int   u32;
typedef __attribute__((ext_vector_type(8))) short  short8;   // 8 bf16 (4 VGPRs)
typedef __attribute__((ext_vector_type(8))) unsigned short ushort8;
typedef __attribute__((ext_vector_type(4))) float  f32x4;

__device__ __forceinline__ u16 f2b(float f) {
    u32 u = __float_as_uint(f);
    u = (u + 0x7fffu + ((u >> 16) & 1u)) >> 16;   // RNE
    return (u16)u;
}
__device__ __forceinline__ float b2f(u16 h) {
    return __uint_as_float(((u32)h) << 16);
}

// ---------------------------------------------------------------------------
// cast fp32 -> bf16, 8 elems/thread
// ---------------------------------------------------------------------------
__global__ __launch_bounds__(256)
void cast_bf16(const float* __restrict__ in, u16* __restrict__ out, int n)
{
    int i = (blockIdx.x * 256 + threadIdx.x) * 8;
    if (i >= n) return;
    float4 a = *(const float4*)(in + i);
    float4 b = *(const float4*)(in + i + 4);
    ushort8 o;
    o[0]=f2b(a.x); o[1]=f2b(a.y); o[2]=f2b(a.z); o[3]=f2b(a.w);
    o[4]=f2b(b.x); o[5]=f2b(b.y); o[6]=f2b(b.z); o[7]=f2b(b.w);
    *(ushort8*)(out + i) = o;
}

// ---------------------------------------------------------------------------
// bf16 MFMA GEMM: C = X[N x K] @ W[M x K]^T. 128x128 tile, BK=32, 4 waves,
// each wave 64x64 (4x4 MFMA 16x16x32). LDS: kg-major planes (stride 2112 B)
// -> conflict-free ds_read_b128 frag reads.
// MODE 0: fp32 C[tok*M + feat]
// MODE 1: bf16 head-major Cb[((b*NH+h)*SEQ+s)*Dh + d]
// MODE 2: bf16 head-transposed Cb[((b*NH+h)*128+d)*SEQ + s]   (Dh=128)
// MODE 3: kv_b split: c<128 -> Cb (kf rows, stride 192); else Cb2 transposed V
// ---------------------------------------------------------------------------
template<int MODE>
__global__ __launch_bounds__(256)
void gemm_bf16(const u16* __restrict__ X, const u16* __restrict__ W,
               float* __restrict__ Cf, u16* __restrict__ Cb, u16* __restrict__ Cb2,
               int K, int M, int Dh)
{
    __shared__ __align__(16) u16 As[4224];   // 4 planes * 1056
    __shared__ __align__(16) u16 Bs[4224];
    const int tid = threadIdx.x;
    const int bn = blockIdx.x * 128;   // feature base
    const int bm = blockIdx.y * 128;   // token base
    const int lane = tid & 63, wv = tid >> 6;
    const int lm = lane & 15, lq = lane >> 4;
    const int wm = (wv >> 1) * 64, wn = (wv & 1) * 64;

    f32x4 acc[4][4] = {};

    for (int k0 = 0; k0 < K; k0 += 32) {
        #pragma unroll
        for (int it = 0; it < 2; ++it) {
            int chunk = tid + it * 256;          // 0..511
            int r = chunk >> 2, c = chunk & 3;
            uint4 va = *(const uint4*)(X + (size_t)(bm + r) * K + k0 + c * 8);
            uint4 vb = *(const uint4*)(W + (size_t)(bn + r) * K + k0 + c * 8);
            *(uint4*)(As + c * 1056 + r * 8) = va;
            *(uint4*)(Bs + c * 1056 + r * 8) = vb;
        }
        __syncthreads();
        short8 af[4], bf[4];
        #pragma unroll
        for (int mt = 0; mt < 4; ++mt)
            af[mt] = *(const short8*)(As + lq * 1056 + (wm + mt * 16 + lm) * 8);
        #pragma unroll
        for (int nt = 0; nt < 4; ++nt)
            bf[nt] = *(const short8*)(Bs + lq * 1056 + (wn + nt * 16 + lm) * 8);
        #pragma unroll
        for (int mt = 0; mt < 4; ++mt)
            #pragma unroll
            for (int nt = 0; nt < 4; ++nt)
                acc[mt][nt] = __builtin_amdgcn_mfma_f32_16x16x32_bf16(
                    af[mt], bf[nt], acc[mt][nt], 0, 0, 0);
        __syncthreads();
    }

    // epilogue: C/D layout col=lane&15, row=(lane>>4)*4+i  [m89-verified]
    #pragma unroll
    for (int mt = 0; mt < 4; ++mt) {
        int token0 = bm + wm + mt * 16 + lq * 4;
        #pragma unroll
        for (int nt = 0; nt < 4; ++nt) {
            int feat = bn + wn + nt * 16 + lm;
            #pragma unroll
            for (int i = 0; i < 4; ++i) {
                float v = acc[mt][nt][i];
                int tok = token0 + i;
                if (MODE == 0) {
                    Cf[(size_t)tok * M + feat] = v;
                } else if (MODE == 1) {
                    int h2 = feat / Dh, d = feat - h2 * Dh;
                    int b2 = tok >> 10, s2 = tok & (SEQ - 1);
                    Cb[((size_t)((b2 * NH + h2) * SEQ + s2)) * Dh + d] = f2b(v);
                } else if (MODE == 2) {
                    int h2 = feat >> 7, d = feat & 127;
                    int b2 = tok >> 10, s2 = tok & (SEQ - 1);
                    Cb[((size_t)((b2 * NH + h2) * 128 + d)) * SEQ + s2] = f2b(v);
                } else {
                    int h2 = feat >> 8, c = feat & 255;
                    int b2 = tok >> 10, s2 = tok & (SEQ - 1);
                    if (c < 128)
                        Cb[((size_t)((b2 * NH + h2) * SEQ + s2)) * DQ + c] = f2b(v);
                    else
                        Cb2[((size_t)((b2 * NH + h2) * 128 + (c - 128))) * SEQ + s2] = f2b(v);
                }
            }
        }
    }
}

// ---------------------------------------------------------------------------
// RMSNorm fp32 in -> bf16 out
// ---------------------------------------------------------------------------
__global__ __launch_bounds__(256)
void rmsnorm_k(const float* __restrict__ in, int in_stride,
               u16* __restrict__ out, int out_stride,
               const float* __restrict__ w, int D)
{
    const int row = blockIdx.x;
    const float* x = in + (size_t)row * in_stride;
    u16* y = out + (size_t)row * out_stride;
    float ss = 0.f;
    for (int d = threadIdx.x; d < D; d += 256) { float v = x[d]; ss += v * v; }
    __shared__ float red[256];
    red[threadIdx.x] = ss;
    __syncthreads();
    for (int off = 128; off > 0; off >>= 1) {
        if (threadIdx.x < off) red[threadIdx.x] += red[threadIdx.x + off];
        __syncthreads();
    }
    float inv = rsqrtf(red[0] / (float)D + EPSV);
    for (int d = threadIdx.x; d < D; d += 256) y[d] = f2b(x[d] * inv * w[d]);
}

// ---------------------------------------------------------------------------
// RoPE on qf bf16 in place. qf [b,h,s,192], rope on last 64 dims.
// ---------------------------------------------------------------------------
__global__ __launch_bounds__(256)
void rope_q_k(u16* __restrict__ qf)
{
    int t = blockIdx.x * 256 + threadIdx.x;        // B*H*S*32
    int i  = t & 31;
    int s  = (t >> 5) & (SEQ - 1);
    int bh = t >> 15;
    float inv_freq = powf(10000.f, -(float)i / 32.f);
    float ang = (float)s * inv_freq;
    float c, sn; sincosf(ang, &sn, &c);
    u16* p = qf + ((size_t)bh * SEQ + s) * DQ;
    float x1 = b2f(p[DNOPE + i]), x2 = b2f(p[DNOPE + 32 + i]);
    p[DNOPE + i]      = f2b(x1 * c - x2 * sn);
    p[DNOPE + 32 + i] = f2b(x2 * c + x1 * sn);
}

// kf[b,h,s,128:192] = rope(k_pe) from kv_a fp32 [b,s,1536] cols 512+h*64
__global__ __launch_bounds__(256)
void rope_k_k(const float* __restrict__ kva, u16* __restrict__ kf)
{
    int t = blockIdx.x * 256 + threadIdx.x;        // B*H*S*32
    int i  = t & 31;
    int s  = (t >> 5) & (SEQ - 1);
    int bh = t >> 15;
    int h = bh & (NH - 1), bb = bh >> 4;
    float inv_freq = powf(10000.f, -(float)i / 32.f);
    float ang = (float)s * inv_freq;
    float c, sn; sincosf(ang, &sn, &c);
    const float* src = kva + ((size_t)(bb * SEQ + s)) * 1536 + KVRANK + h * DROPE;
    float x1 = src[i], x2 = src[32 + i];
    u16* dst = kf + ((size_t)bh * SEQ + s) * DQ + DNOPE;
    dst[i]      = f2b(x1 * c - x2 * sn);
    dst[32 + i] = f2b(x2 * c + x1 * sn);
}

// ---------------------------------------------------------------------------
// MFMA flash attention. Q,K: [b,h,s,DQK] bf16. Vt: [b,h,d,SEQ] bf16 (pre-
// transposed). ctx out token-major bf16 [b,s,h*128].
// Block = 4 waves; q-tile 64 (16 rows/wave); 32-key tiles, online softmax.
// ---------------------------------------------------------------------------
template<int DQK>
__global__ __launch_bounds__(256)
void flash_mfma(const u16* __restrict__ Q, const u16* __restrict__ Kf,
                const u16* __restrict__ Vt, u16* __restrict__ ctx_out, float scale)
{
    constexpr int KROW = DQK + 8;       // ushorts per K row (16B-aligned stride)
    constexpr int CPR  = DQK / 8;       // 16B chunks per K row
    __shared__ __align__(16) u16 Ks[32 * KROW];
    __shared__ __align__(16) u16 Vs[128 * 40];   // [d][key tile], pad 40
    __shared__ __align__(16) u16 Ps[4 * 16 * 40];
    const int tid = threadIdx.x, lane = tid & 63, wv = tid >> 6;
    const int lm = lane & 15, lq = lane >> 4;
    const int qt = blockIdx.x, h = blockIdx.y, bb = blockIdx.z;
    const size_t bh = (size_t)bb * NH + h;
    const u16* Qb = Q + (bh * SEQ + qt * 64 + wv * 16) * (size_t)DQK;
    const u16* Kb = Kf + bh * SEQ * (size_t)DQK;
    const u16* Vb = Vt + bh * (size_t)128 * SEQ;

    short8 qfrag[DQK / 32];
    #pragma unroll
    for (int ks = 0; ks < DQK / 32; ++ks)
        qfrag[ks] = *(const short8*)(Qb + lm * DQK + ks * 32 + lq * 8);

    float m_i[4], l_i[4];
    #pragma unroll
    for (int i = 0; i < 4; ++i) { m_i[i] = -INFINITY; l_i[i] = 0.f; }
    f32x4 oacc[8] = {};

    for (int kt = 0; kt < SEQ / 32; ++kt) {
        // stage K tile (coalesced 16B loads, sequential LDS writes)
        for (int chunk = tid; chunk < 32 * CPR; chunk += 256) {
            int key = chunk / CPR, c = chunk % CPR;
            *(uint4*)(Ks + key * KROW + c * 8) =
                *(const uint4*)(Kb + ((size_t)(kt * 32 + key)) * DQK + c * 8);
        }
        // stage V^T tile: rows d=0..127, 32 keys each
        #pragma unroll
        for (int it = 0; it < 2; ++it) {
            int chunk = tid + it * 256;
            int d = chunk >> 2, kc = chunk & 3;
            *(uint4*)(Vs + d * 40 + kc * 8) =
                *(const uint4*)(Vb + (size_t)d * SEQ + kt * 32 + kc * 8);
        }
        __syncthreads();

        // scores: S[16x32] = Q(16xDQK) . K^T
        f32x4 sacc[2] = {};
        #pragma unroll
        for (int kb = 0; kb < 2; ++kb)
            #pragma unroll
            for (int ks = 0; ks < DQK / 32; ++ks) {
                short8 kfr = *(const short8*)(Ks + (kb * 16 + lm) * KROW + ks * 32 + lq * 8);
                sacc[kb] = __builtin_amdgcn_mfma_f32_16x16x32_bf16(
                    qfrag[ks], kfr, sacc[kb], 0, 0, 0);
            }

        // online softmax (rows = lq*4+i, cols = kb*16+lm)
        float p0[4], p1[4], alpha[4];
        #pragma unroll
        for (int i = 0; i < 4; ++i) {
            float s0 = sacc[0][i] * scale, s1 = sacc[1][i] * scale;
            float mx = fmaxf(s0, s1);
            mx = fmaxf(mx, __shfl_xor(mx, 1));
            mx = fmaxf(mx, __shfl_xor(mx, 2));
            mx = fmaxf(mx, __shfl_xor(mx, 4));
            mx = fmaxf(mx, __shfl_xor(mx, 8));
            float mnew = fmaxf(m_i[i], mx);
            p0[i] = __expf(s0 - mnew);
            p1[i] = __expf(s1 - mnew);
            float sum = p0[i] + p1[i];
            sum += __shfl_xor(sum, 1);
            sum += __shfl_xor(sum, 2);
            sum += __shfl_xor(sum, 4);
            sum += __shfl_xor(sum, 8);
            alpha[i] = __expf(m_i[i] - mnew);
            l_i[i] = l_i[i] * alpha[i] + sum;
            m_i[i] = mnew;
        }

        // P: C-layout -> A-layout via per-wave LDS (stride 40 u16 = 80 B)
        u16* Pw = Ps + wv * 640;
        #pragma unroll
        for (int i = 0; i < 4; ++i) {
            Pw[(lq * 4 + i) * 40 + lm]      = f2b(p0[i]);
            Pw[(lq * 4 + i) * 40 + 16 + lm] = f2b(p1[i]);
        }
        __syncthreads();
        short8 pfrag = *(const short8*)(Pw + lm * 40 + lq * 8);

        // O += P . V  (8 col-tiles of 16)
        #pragma unroll
        for (int nt = 0; nt < 8; ++nt) {
            #pragma unroll
            for (int i = 0; i < 4; ++i) oacc[nt][i] *= alpha[i];
            short8 vfr = *(const short8*)(Vs + (nt * 16 + lm) * 40 + lq * 8);
            oacc[nt] = __builtin_amdgcn_mfma_f32_16x16x32_bf16(
                pfrag, vfr, oacc[nt], 0, 0, 0);
        }
        __syncthreads();
    }

    // epilogue: rows -> s, cols -> d; store bf16 token-major
    int s0 = qt * 64 + wv * 16 + lq * 4;
    #pragma unroll
    for (int i = 0; i < 4; ++i) {
        float inv = 1.f / l_i[i];
        u16* dst = ctx_out + ((size_t)(bb * SEQ + s0 + i) * NH + h) * 128;
        #pragma unroll
        for (int nt = 0; nt < 8; ++nt)
            dst[nt * 16 + lm] = f2b(oacc[nt][i] * inv);
    }
}

// ---------------------------------------------------------------------------
// Gate + combine (fp32): out = g0*main + g1*pattern
// ---------------------------------------------------------------------------
__global__ __launch_bounds__(256)
void gate_combine(const float* __restrict__ x, const float* __restrict__ gw,
                  const float* __restrict__ gb,
                  const float* __restrict__ mo, const float* __restrict__ po,
                  float* __restrict__ out)
{
    const int tok = blockIdx.x;
    const float* xr = x + (size_t)tok * HIDN;
    float d0 = 0.f, d1 = 0.f;
    for (int i = threadIdx.x; i < HIDN; i += 256) {
        float v = xr[i];
        d0 += v * gw[i];
        d1 += v * gw[HIDN + i];
    }
    __shared__ float r0[256], r1[256];
    r0[threadIdx.x] = d0; r1[threadIdx.x] = d1;
    __syncthreads();
    for (int off = 128; off > 0; off >>= 1) {
        if (threadIdx.x < off) {
            r0[threadIdx.x] += r0[threadIdx.x + off];
            r1[threadIdx.x] += r1[threadIdx.x + off];
        }
        __syncthreads();
    }
    float l0 = r0[0] + gb[0], l1 = r1[0] + gb[1];
    float m = fmaxf(l0, l1);
    float e0 = __expf(l0 - m), e1 = __expf(l1 - m);
    float g0 = e0 / (e0 + e1), g1 = e1 / (e0 + e1);
    const float* mr = mo + (size_t)tok * HIDN;
    const float* pr = po + (size_t)tok * HIDN;
    float* orow = out + (size_t)tok * HIDN;
    for (int i = threadIdx.x; i < HIDN; i += 256)
        orow[i] = g0 * mr[i] + g1 * pr[i];
}

// ---------------------------------------------------------------------------
extern "C" void kernel_launch(void* const* d_in, const int* in_sizes, int n_in,
                              void* d_out, int out_size, void* d_ws, size_t ws_size,
                              hipStream_t stream)
{
    const float* X        = (const float*)d_in[0];
    const float* q_a_w    = (const float*)d_in[1];
    const float* q_a_ln_w = (const float*)d_in[2];
    const float* q_b_w    = (const float*)d_in[3];
    const float* kv_a_w   = (const float*)d_in[4];
    const float* kv_a_ln_w= (const float*)d_in[5];
    const float* kv_b_w   = (const float*)d_in[6];
    const float* o_w      = (const float*)d_in[7];
    const float* sp_q_w   = (const float*)d_in[8];
    const float* sp_k_w   = (const float*)d_in[9];
    const float* sp_v_w   = (const float*)d_in[10];
    const float* sp_o_w   = (const float*)d_in[11];
    const float* gate_w   = (const float*)d_in[12];
    const float* gate_b   = (const float*)d_in[13];
    float* out = (float*)d_out;

    // workspace carve (256B aligned)
    char* p = (char*)d_ws;
    auto alloc = [&](size_t bytes) -> char* {
        char* r = p; p += (bytes + 255) & ~(size_t)255; return r;
    };
    float* q_mid   = (float*)alloc((size_t)NTOK * QRANK * 4);    // 12.6 MB
    float* kv_a    = (float*)alloc((size_t)NTOK * 1536 * 4);     // 12.6 MB
    u16* Xb        = (u16*)alloc((size_t)NTOK * HIDN * 2);
    u16* q_a_wb    = (u16*)alloc((size_t)QRANK * HIDN * 2);
    u16* q_b_wb    = (u16*)alloc((size_t)NH * DQ * QRANK * 2);
    u16* kv_a_wb   = (u16*)alloc((size_t)1536 * HIDN * 2);
    u16* kv_b_wb   = (u16*)alloc((size_t)NH * 256 * KVRANK * 2);
    u16* o_wb      = (u16*)alloc((size_t)HIDN * HIDN * 2);
    u16* sp_q_wb   = (u16*)alloc((size_t)HIDN * HIDN * 2);
    u16* sp_k_wb   = (u16*)alloc((size_t)HIDN * HIDN * 2);
    u16* sp_v_wb   = (u16*)alloc((size_t)HIDN * HIDN * 2);
    u16* sp_o_wb   = (u16*)alloc((size_t)HIDN * HIDN * 2);
    u16* q_midb    = (u16*)alloc((size_t)NTOK * QRANK * 2);
    u16* kv_lnb    = (u16*)alloc((size_t)NTOK * KVRANK * 2);
    u16* qf        = (u16*)alloc((size_t)NTOK * NH * DQ * 2);
    u16* kf        = (u16*)alloc((size_t)NTOK * NH * DQ * 2);
    u16* Vtg       = (u16*)alloc((size_t)NBATCH * NH * 128 * SEQ * 2);
    u16* ctx       = (u16*)alloc((size_t)NTOK * HIDN * 2);
    // aliases (stream-ordered disjoint lifetimes)
    float* patout = q_mid;         // q_mid+kv_a region (25.2 MB) >= 16.8 MB
    u16* pq  = qf;
    u16* pk  = kf;
    u16* pvt = Vtg;
    u16* p_ctx = ctx;

    dim3 blk(256);

    // casts
    struct { const float* s; u16* d; int n; } casts[10] = {
        {X, Xb, NTOK * HIDN},
        {q_a_w, q_a_wb, QRANK * HIDN},
        {q_b_w, q_b_wb, NH * DQ * QRANK},
        {kv_a_w, kv_a_wb, 1536 * HIDN},
        {kv_b_w, kv_b_wb, NH * 256 * KVRANK},
        {o_w, o_wb, HIDN * HIDN},
        {sp_q_w, sp_q_wb, HIDN * HIDN},
        {sp_k_w, sp_k_wb, HIDN * HIDN},
        {sp_v_w, sp_v_wb, HIDN * HIDN},
        {sp_o_w, sp_o_wb, HIDN * HIDN},
    };
    for (int i = 0; i < 10; ++i)
        cast_bf16<<<dim3(casts[i].n / 2048), blk, 0, stream>>>(casts[i].s, casts[i].d, casts[i].n);

    // main branch projections
    gemm_bf16<0><<<dim3(QRANK/128, NTOK/128), blk, 0, stream>>>(
        Xb, q_a_wb, q_mid, nullptr, nullptr, HIDN, QRANK, 0);
    rmsnorm_k<<<dim3(NTOK), blk, 0, stream>>>(q_mid, QRANK, q_midb, QRANK, q_a_ln_w, QRANK);
    gemm_bf16<1><<<dim3(NH*DQ/128, NTOK/128), blk, 0, stream>>>(
        q_midb, q_b_wb, nullptr, qf, nullptr, QRANK, NH*DQ, DQ);
    gemm_bf16<0><<<dim3(1536/128, NTOK/128), blk, 0, stream>>>(
        Xb, kv_a_wb, kv_a, nullptr, nullptr, HIDN, 1536, 0);
    rmsnorm_k<<<dim3(NTOK), blk, 0, stream>>>(kv_a, 1536, kv_lnb, KVRANK, kv_a_ln_w, KVRANK);
    gemm_bf16<3><<<dim3(NH*256/128, NTOK/128), blk, 0, stream>>>(
        kv_lnb, kv_b_wb, nullptr, kf, Vtg, KVRANK, NH*256, 0);

    // rope
    rope_q_k<<<dim3(NBATCH*NH*SEQ*32/256), blk, 0, stream>>>(qf);
    rope_k_k<<<dim3(NBATCH*NH*SEQ*32/256), blk, 0, stream>>>(kv_a, kf);

    // main attention
    float scale_main = 1.0f / sqrtf((float)DQ);
    flash_mfma<DQ><<<dim3(SEQ/64, NH, NBATCH), blk, 0, stream>>>(
        qf, kf, Vtg, ctx, scale_main);
    gemm_bf16<0><<<dim3(HIDN/128, NTOK/128), blk, 0, stream>>>(
        ctx, o_wb, out, nullptr, nullptr, HIDN, HIDN, 0);   // mainout -> d_out

    // pattern branch
    gemm_bf16<1><<<dim3(HIDN/128, NTOK/128), blk, 0, stream>>>(
        Xb, sp_q_wb, nullptr, pq, nullptr, HIDN, HIDN, 128);
    gemm_bf16<1><<<dim3(HIDN/128, NTOK/128), blk, 0, stream>>>(
        Xb, sp_k_wb, nullptr, pk, nullptr, HIDN, HIDN, 128);
    gemm_bf16<2><<<dim3(HIDN/128, NTOK/128), blk, 0, stream>>>(
        Xb, sp_v_wb, nullptr, pvt, nullptr, HIDN, HIDN, 128);
    float scale_pat = 1.0f / sqrtf(128.0f);
    flash_mfma<128><<<dim3(SEQ/64, NH, NBATCH), blk, 0, stream>>>(
        pq, pk, pvt, p_ctx, scale_pat);
    gemm_bf16<0><<<dim3(HIDN/128, NTOK/128), blk, 0, stream>>>(
        p_ctx, sp_o_wb, patout, nullptr, nullptr, HIDN, HIDN, 0);

    // gate + combine (reads d_out as main_out, overwrites d_out)
    gate_combine<<<dim3(NTOK), blk, 0, stream>>>(X, gate_w, gate_b, out, patout, out);
}

// Round 3
// 687.391 us; speedup vs baseline: 5.6710x; 1.2007x over previous
//
#include <hip/hip_runtime.h>
#include <math.h>
#include <stdint.h>

#define HIDN  2048
#define NH    16
#define DNOPE 128
#define DROPE 64
#define DQ    192
#define DV    128
#define QRANK 1536
#define KVRANK 512
#define SEQ   1024
#define NBATCH 2
#define NTOK  (NBATCH*SEQ)
#define EPSV  1e-6f

typedef unsigned short u16;
typedef unsigned int   u32;
typedef __attribute__((ext_vector_type(8))) short  short8;   // 8 bf16 (4 VGPRs)
typedef __attribute__((ext_vector_type(8))) unsigned short ushort8;
typedef __attribute__((ext_vector_type(4))) float  f32x4;

__device__ __forceinline__ u16 f2b(float f) {
    u32 u = __float_as_uint(f);
    u = (u + 0x7fffu + ((u >> 16) & 1u)) >> 16;   // RNE
    return (u16)u;
}
__device__ __forceinline__ float b2f(u16 h) {
    return __uint_as_float(((u32)h) << 16);
}

// async global->LDS, 16B per lane; LDS dest = wave-uniform base + lane*16
__device__ __forceinline__ void async_copy16(const u16* g, u16* l) {
    __builtin_amdgcn_global_load_lds(
        (const __attribute__((address_space(1))) u32*)g,
        (__attribute__((address_space(3))) u32*)l,
        16, 0, 0);
}

// ---------------------------------------------------------------------------
// Fused cast fp32 -> bf16 over 10 segments, one dispatch. 8 elems/thread.
// ---------------------------------------------------------------------------
struct CastArgs {
    const float* s[10];
    u16* d[10];
    int cum[11];       // cumulative chunk counts, cum[0]=0
};
__global__ __launch_bounds__(256)
void cast_all(CastArgs a, int total_chunks)
{
    int c = blockIdx.x * 256 + threadIdx.x;
    if (c >= total_chunks) return;
    int seg = 0;
    #pragma unroll
    for (int i = 1; i < 10; ++i) seg += (c >= a.cum[i]) ? 1 : 0;
    int local = c - a.cum[seg];
    const float* src = a.s[seg] + (size_t)local * 8;
    u16* dst = a.d[seg] + (size_t)local * 8;
    float4 x = *(const float4*)(src);
    float4 y = *(const float4*)(src + 4);
    ushort8 o;
    o[0]=f2b(x.x); o[1]=f2b(x.y); o[2]=f2b(x.z); o[3]=f2b(x.w);
    o[4]=f2b(y.x); o[5]=f2b(y.y); o[6]=f2b(y.z); o[7]=f2b(y.w);
    *(ushort8*)(dst) = o;
}

// ---------------------------------------------------------------------------
// bf16 MFMA GEMM (m97 structure): C = X[N x K] @ W[M x K]^T.
// 128x128 tile, BK=32, 4 waves x (64x64), async global_load_lds width-16.
// LDS: row-major [128][32] u16, no pad.
// MODE 0: fp32 C[tok*M + feat]            (M = row stride)
// MODE 1: bf16 head-major Cb[((b*NH+h)*SEQ+s)*Dh + d]
// MODE 3: kv_b split: c<128 -> Cb (kf rows, stride 192); else Cb2 V^T
// MODE 4: spqkv: w=feat>>11: 0->Cb (pq), 1->Cb2 (pk) head-major Dh=128;
//                2->Cb3 (pv) transposed [b,h,d,SEQ]
// ---------------------------------------------------------------------------
template<int MODE>
__global__ __launch_bounds__(256)
void gemm_bf16(const u16* __restrict__ X, const u16* __restrict__ W,
               float* __restrict__ Cf, u16* __restrict__ Cb,
               u16* __restrict__ Cb2, u16* __restrict__ Cb3,
               int K, int M, int Dh)
{
    __shared__ __align__(16) u16 As[128 * 32];
    __shared__ __align__(16) u16 Bs[128 * 32];
    const int tid = threadIdx.x;
    const int bn = blockIdx.x * 128;   // feature base
    const int bm = blockIdx.y * 128;   // token base
    const int lane = tid & 63, wv = tid >> 6;
    const int lm = lane & 15, lq = lane >> 4;
    const int wm = (wv >> 1) * 64, wn = (wv & 1) * 64;

    f32x4 acc[4][4] = {};

    for (int k0 = 0; k0 < K; k0 += 32) {
        #pragma unroll
        for (int it = 0; it < 2; ++it) {
            int base = wv * 64 + it * 256;            // wave-uniform chunk base
            int chunk = base + lane;
            int r = chunk >> 2, c = chunk & 3;
            async_copy16(X + (size_t)(bm + r) * K + k0 + c * 8, As + base * 8);
            async_copy16(W + (size_t)(bn + r) * K + k0 + c * 8, Bs + base * 8);
        }
        __syncthreads();
        short8 af[4], bf[4];
        #pragma unroll
        for (int mt = 0; mt < 4; ++mt)
            af[mt] = *(const short8*)(As + (wm + mt * 16 + lm) * 32 + lq * 8);
        #pragma unroll
        for (int nt = 0; nt < 4; ++nt)
            bf[nt] = *(const short8*)(Bs + (wn + nt * 16 + lm) * 32 + lq * 8);
        #pragma unroll
        for (int mt = 0; mt < 4; ++mt)
            #pragma unroll
            for (int nt = 0; nt < 4; ++nt)
                acc[mt][nt] = __builtin_amdgcn_mfma_f32_16x16x32_bf16(
                    af[mt], bf[nt], acc[mt][nt], 0, 0, 0);
        __syncthreads();
    }

    // epilogue: C/D layout col=lane&15, row=(lane>>4)*4+i  [m89-verified]
    #pragma unroll
    for (int mt = 0; mt < 4; ++mt) {
        int token0 = bm + wm + mt * 16 + lq * 4;
        #pragma unroll
        for (int nt = 0; nt < 4; ++nt) {
            int feat = bn + wn + nt * 16 + lm;
            #pragma unroll
            for (int i = 0; i < 4; ++i) {
                float v = acc[mt][nt][i];
                int tok = token0 + i;
                int b2 = tok >> 10, s2 = tok & (SEQ - 1);
                if (MODE == 0) {
                    Cf[(size_t)tok * M + feat] = v;
                } else if (MODE == 1) {
                    int h2 = feat / Dh, d = feat - h2 * Dh;
                    Cb[((size_t)((b2 * NH + h2) * SEQ + s2)) * Dh + d] = f2b(v);
                } else if (MODE == 3) {
                    int h2 = feat >> 8, c = feat & 255;
                    if (c < 128)
                        Cb[((size_t)((b2 * NH + h2) * SEQ + s2)) * DQ + c] = f2b(v);
                    else
                        Cb2[((size_t)((b2 * NH + h2) * 128 + (c - 128))) * SEQ + s2] = f2b(v);
                } else { // MODE 4
                    int wsel = feat >> 11;
                    int f2 = feat & 2047;
                    int h2 = f2 >> 7, d = f2 & 127;
                    if (wsel == 0)
                        Cb[((size_t)((b2 * NH + h2) * SEQ + s2)) * 128 + d] = f2b(v);
                    else if (wsel == 1)
                        Cb2[((size_t)((b2 * NH + h2) * SEQ + s2)) * 128 + d] = f2b(v);
                    else
                        Cb3[((size_t)((b2 * NH + h2) * 128 + d)) * SEQ + s2] = f2b(v);
                }
            }
        }
    }
}

// ---------------------------------------------------------------------------
// RMSNorm fp32 in -> bf16 out
// ---------------------------------------------------------------------------
__global__ __launch_bounds__(256)
void rmsnorm_k(const float* __restrict__ in, int in_stride,
               u16* __restrict__ out, int out_stride,
               const float* __restrict__ w, int D)
{
    const int row = blockIdx.x;
    const float* x = in + (size_t)row * in_stride;
    u16* y = out + (size_t)row * out_stride;
    float ss = 0.f;
    for (int d = threadIdx.x; d < D; d += 256) { float v = x[d]; ss += v * v; }
    __shared__ float red[256];
    red[threadIdx.x] = ss;
    __syncthreads();
    for (int off = 128; off > 0; off >>= 1) {
        if (threadIdx.x < off) red[threadIdx.x] += red[threadIdx.x + off];
        __syncthreads();
    }
    float inv = rsqrtf(red[0] / (float)D + EPSV);
    for (int d = threadIdx.x; d < D; d += 256) y[d] = f2b(x[d] * inv * w[d]);
}

// ---------------------------------------------------------------------------
// RoPE on qf bf16 in place. qf [b,h,s,192], rope on last 64 dims.
// ---------------------------------------------------------------------------
__global__ __launch_bounds__(256)
void rope_q_k(u16* __restrict__ qf)
{
    int t = blockIdx.x * 256 + threadIdx.x;        // B*H*S*32
    int i  = t & 31;
    int s  = (t >> 5) & (SEQ - 1);
    int bh = t >> 15;
    float inv_freq = powf(10000.f, -(float)i / 32.f);
    float ang = (float)s * inv_freq;
    float c, sn; sincosf(ang, &sn, &c);
    u16* p = qf + ((size_t)bh * SEQ + s) * DQ;
    float x1 = b2f(p[DNOPE + i]), x2 = b2f(p[DNOPE + 32 + i]);
    p[DNOPE + i]      = f2b(x1 * c - x2 * sn);
    p[DNOPE + 32 + i] = f2b(x2 * c + x1 * sn);
}

// kf[b,h,s,128:192] = rope(k_pe); src fp32 rows stride `stride`, col off 512+h*64
__global__ __launch_bounds__(256)
void rope_k_k(const float* __restrict__ kva, int stride, u16* __restrict__ kf)
{
    int t = blockIdx.x * 256 + threadIdx.x;        // B*H*S*32
    int i  = t & 31;
    int s  = (t >> 5) & (SEQ - 1);
    int bh = t >> 15;
    int h = bh & (NH - 1), bb = bh >> 4;
    float inv_freq = powf(10000.f, -(float)i / 32.f);
    float ang = (float)s * inv_freq;
    float c, sn; sincosf(ang, &sn, &c);
    const float* src = kva + ((size_t)(bb * SEQ + s)) * stride + KVRANK + h * DROPE;
    float x1 = src[i], x2 = src[32 + i];
    u16* dst = kf + ((size_t)bh * SEQ + s) * DQ + DNOPE;
    dst[i]      = f2b(x1 * c - x2 * sn);
    dst[32 + i] = f2b(x2 * c + x1 * sn);
}

// ---------------------------------------------------------------------------
// MFMA flash attention. Q,K: [b,h,s,DQK] bf16. Vt: [b,h,d,SEQ] bf16.
// ctx out token-major bf16 [b,s,h*128]. 2 barriers per key-tile.
// ---------------------------------------------------------------------------
template<int DQK>
__global__ __launch_bounds__(256)
void flash_mfma(const u16* __restrict__ Q, const u16* __restrict__ Kf,
                const u16* __restrict__ Vt, u16* __restrict__ ctx_out, float scale)
{
    constexpr int KROW = DQK + 8;       // u16 per K row (16B-aligned stride)
    constexpr int CPR  = DQK / 8;       // 16B chunks per K row
    __shared__ __align__(16) u16 Ks[32 * KROW];
    __shared__ __align__(16) u16 Vs[128 * 40];   // [d][key tile], pad 40
    __shared__ __align__(16) u16 Ps[4 * 16 * 40];
    const int tid = threadIdx.x, lane = tid & 63, wv = tid >> 6;
    const int lm = lane & 15, lq = lane >> 4;
    const int qt = blockIdx.x, h = blockIdx.y, bb = blockIdx.z;
    const size_t bh = (size_t)bb * NH + h;
    const u16* Qb = Q + (bh * SEQ + qt * 64 + wv * 16) * (size_t)DQK;
    const u16* Kb = Kf + bh * SEQ * (size_t)DQK;
    const u16* Vb = Vt + bh * (size_t)128 * SEQ;

    short8 qfrag[DQK / 32];
    #pragma unroll
    for (int ks = 0; ks < DQK / 32; ++ks)
        qfrag[ks] = *(const short8*)(Qb + lm * DQK + ks * 32 + lq * 8);

    float m_i[4], l_i[4];
    #pragma unroll
    for (int i = 0; i < 4; ++i) { m_i[i] = -INFINITY; l_i[i] = 0.f; }
    f32x4 oacc[8] = {};

    for (int kt = 0; kt < SEQ / 32; ++kt) {
        for (int chunk = tid; chunk < 32 * CPR; chunk += 256) {
            int key = chunk / CPR, c = chunk % CPR;
            *(uint4*)(Ks + key * KROW + c * 8) =
                *(const uint4*)(Kb + ((size_t)(kt * 32 + key)) * DQK + c * 8);
        }
        #pragma unroll
        for (int it = 0; it < 2; ++it) {
            int chunk = tid + it * 256;
            int d = chunk >> 2, kc = chunk & 3;
            *(uint4*)(Vs + d * 40 + kc * 8) =
                *(const uint4*)(Vb + (size_t)d * SEQ + kt * 32 + kc * 8);
        }
        __syncthreads();

        // scores: S[16x32] = Q(16xDQK) . K^T
        f32x4 sacc[2] = {};
        #pragma unroll
        for (int kb = 0; kb < 2; ++kb)
            #pragma unroll
            for (int ks = 0; ks < DQK / 32; ++ks) {
                short8 kfr = *(const short8*)(Ks + (kb * 16 + lm) * KROW + ks * 32 + lq * 8);
                sacc[kb] = __builtin_amdgcn_mfma_f32_16x16x32_bf16(
                    qfrag[ks], kfr, sacc[kb], 0, 0, 0);
            }

        // online softmax (rows = lq*4+i, cols = kb*16+lm)
        float p0[4], p1[4], alpha[4];
        #pragma unroll
        for (int i = 0; i < 4; ++i) {
            float s0 = sacc[0][i] * scale, s1 = sacc[1][i] * scale;
            float mx = fmaxf(s0, s1);
            mx = fmaxf(mx, __shfl_xor(mx, 1));
            mx = fmaxf(mx, __shfl_xor(mx, 2));
            mx = fmaxf(mx, __shfl_xor(mx, 4));
            mx = fmaxf(mx, __shfl_xor(mx, 8));
            float mnew = fmaxf(m_i[i], mx);
            p0[i] = __expf(s0 - mnew);
            p1[i] = __expf(s1 - mnew);
            float sum = p0[i] + p1[i];
            sum += __shfl_xor(sum, 1);
            sum += __shfl_xor(sum, 2);
            sum += __shfl_xor(sum, 4);
            sum += __shfl_xor(sum, 8);
            alpha[i] = __expf(m_i[i] - mnew);
            l_i[i] = l_i[i] * alpha[i] + sum;
            m_i[i] = mnew;
        }

        // P: C-layout -> A-layout via per-wave LDS (wave-local: no barrier)
        u16* Pw = Ps + wv * 640;
        #pragma unroll
        for (int i = 0; i < 4; ++i) {
            Pw[(lq * 4 + i) * 40 + lm]      = f2b(p0[i]);
            Pw[(lq * 4 + i) * 40 + 16 + lm] = f2b(p1[i]);
        }
        short8 pfrag = *(const short8*)(Pw + lm * 40 + lq * 8);

        // O += P . V  (8 col-tiles of 16)
        #pragma unroll
        for (int nt = 0; nt < 8; ++nt) {
            #pragma unroll
            for (int i = 0; i < 4; ++i) oacc[nt][i] *= alpha[i];
            short8 vfr = *(const short8*)(Vs + (nt * 16 + lm) * 40 + lq * 8);
            oacc[nt] = __builtin_amdgcn_mfma_f32_16x16x32_bf16(
                pfrag, vfr, oacc[nt], 0, 0, 0);
        }
        __syncthreads();
    }

    int s0 = qt * 64 + wv * 16 + lq * 4;
    #pragma unroll
    for (int i = 0; i < 4; ++i) {
        float inv = 1.f / l_i[i];
        u16* dst = ctx_out + ((size_t)(bb * SEQ + s0 + i) * NH + h) * 128;
        #pragma unroll
        for (int nt = 0; nt < 8; ++nt)
            dst[nt * 16 + lm] = f2b(oacc[nt][i] * inv);
    }
}

// ---------------------------------------------------------------------------
// Gate + combine (fp32): out = g0*main + g1*pattern
// ---------------------------------------------------------------------------
__global__ __launch_bounds__(256)
void gate_combine(const float* __restrict__ x, const float* __restrict__ gw,
                  const float* __restrict__ gb,
                  const float* __restrict__ mo, const float* __restrict__ po,
                  float* __restrict__ out)
{
    const int tok = blockIdx.x;
    const float* xr = x + (size_t)tok * HIDN;
    float d0 = 0.f, d1 = 0.f;
    for (int i = threadIdx.x; i < HIDN; i += 256) {
        float v = xr[i];
        d0 += v * gw[i];
        d1 += v * gw[HIDN + i];
    }
    __shared__ float r0[256], r1[256];
    r0[threadIdx.x] = d0; r1[threadIdx.x] = d1;
    __syncthreads();
    for (int off = 128; off > 0; off >>= 1) {
        if (threadIdx.x < off) {
            r0[threadIdx.x] += r0[threadIdx.x + off];
            r1[threadIdx.x] += r1[threadIdx.x + off];
        }
        __syncthreads();
    }
    float l0 = r0[0] + gb[0], l1 = r1[0] + gb[1];
    float m = fmaxf(l0, l1);
    float e0 = __expf(l0 - m), e1 = __expf(l1 - m);
    float g0 = e0 / (e0 + e1), g1 = e1 / (e0 + e1);
    const float* mr = mo + (size_t)tok * HIDN;
    const float* pr = po + (size_t)tok * HIDN;
    float* orow = out + (size_t)tok * HIDN;
    for (int i = threadIdx.x; i < HIDN; i += 256)
        orow[i] = g0 * mr[i] + g1 * pr[i];
}

// ---------------------------------------------------------------------------
extern "C" void kernel_launch(void* const* d_in, const int* in_sizes, int n_in,
                              void* d_out, int out_size, void* d_ws, size_t ws_size,
                              hipStream_t stream)
{
    const float* X        = (const float*)d_in[0];
    const float* q_a_w    = (const float*)d_in[1];
    const float* q_a_ln_w = (const float*)d_in[2];
    const float* q_b_w    = (const float*)d_in[3];
    const float* kv_a_w   = (const float*)d_in[4];
    const float* kv_a_ln_w= (const float*)d_in[5];
    const float* kv_b_w   = (const float*)d_in[6];
    const float* o_w      = (const float*)d_in[7];
    const float* sp_q_w   = (const float*)d_in[8];
    const float* sp_k_w   = (const float*)d_in[9];
    const float* sp_v_w   = (const float*)d_in[10];
    const float* sp_o_w   = (const float*)d_in[11];
    const float* gate_w   = (const float*)d_in[12];
    const float* gate_b   = (const float*)d_in[13];
    float* out = (float*)d_out;

    // workspace carve (256B aligned)
    char* p = (char*)d_ws;
    auto alloc = [&](size_t bytes) -> char* {
        char* r = p; p += (bytes + 255) & ~(size_t)255; return r;
    };
    float* amid    = (float*)alloc((size_t)NTOK * 3072 * 4);     // [tok][q_mid|kv_a]
    u16* Xb        = (u16*)alloc((size_t)NTOK * HIDN * 2);
    u16* aw_b      = (u16*)alloc((size_t)3072 * HIDN * 2);       // [q_a_w; kv_a_w]
    u16* q_b_wb    = (u16*)alloc((size_t)NH * DQ * QRANK * 2);
    u16* kv_b_wb   = (u16*)alloc((size_t)NH * 256 * KVRANK * 2);
    u16* o_wb      = (u16*)alloc((size_t)HIDN * HIDN * 2);
    u16* spqkv_wb  = (u16*)alloc((size_t)3 * HIDN * HIDN * 2);   // [spq;spk;spv]
    u16* sp_o_wb   = (u16*)alloc((size_t)HIDN * HIDN * 2);
    u16* q_midb    = (u16*)alloc((size_t)NTOK * QRANK * 2);
    u16* kv_lnb    = (u16*)alloc((size_t)NTOK * KVRANK * 2);
    u16* qf        = (u16*)alloc((size_t)NTOK * NH * DQ * 2);
    u16* kf        = (u16*)alloc((size_t)NTOK * NH * DQ * 2);
    u16* Vtg       = (u16*)alloc((size_t)NBATCH * NH * 128 * SEQ * 2);
    u16* ctx       = (u16*)alloc((size_t)NTOK * HIDN * 2);
    float* patout  = amid;         // amid (25.2 MB) free after rope_k; need 16.8 MB
    u16* pq  = qf;
    u16* pk  = kf;
    u16* pvt = Vtg;
    u16* p_ctx = ctx;

    dim3 blk(256);

    // ---- single fused cast dispatch ----
    CastArgs ca;
    const float* srcs[10] = {X, q_a_w, kv_a_w, q_b_w, kv_b_w, o_w,
                             sp_q_w, sp_k_w, sp_v_w, sp_o_w};
    u16* dsts[10] = {Xb, aw_b, aw_b + (size_t)QRANK * HIDN, q_b_wb, kv_b_wb, o_wb,
                     spqkv_wb, spqkv_wb + (size_t)HIDN * HIDN,
                     spqkv_wb + (size_t)2 * HIDN * HIDN, sp_o_wb};
    int ns[10] = {NTOK * HIDN, QRANK * HIDN, 1536 * HIDN, NH * DQ * QRANK,
                  NH * 256 * KVRANK, HIDN * HIDN, HIDN * HIDN, HIDN * HIDN,
                  HIDN * HIDN, HIDN * HIDN};
    int cum = 0;
    for (int i = 0; i < 10; ++i) {
        ca.s[i] = srcs[i]; ca.d[i] = dsts[i];
        ca.cum[i] = cum; cum += ns[i] / 8;
    }
    ca.cum[10] = cum;
    cast_all<<<dim3((cum + 255) / 256), blk, 0, stream>>>(ca, cum);

    // ---- fused q_a + kv_a projection: [tok][3072] fp32 ----
    gemm_bf16<0><<<dim3(3072/128, NTOK/128), blk, 0, stream>>>(
        Xb, aw_b, amid, nullptr, nullptr, nullptr, HIDN, 3072, 0);
    rmsnorm_k<<<dim3(NTOK), blk, 0, stream>>>(amid, 3072, q_midb, QRANK, q_a_ln_w, QRANK);
    rmsnorm_k<<<dim3(NTOK), blk, 0, stream>>>(amid + QRANK, 3072, kv_lnb, KVRANK, kv_a_ln_w, KVRANK);

    gemm_bf16<1><<<dim3(NH*DQ/128, NTOK/128), blk, 0, stream>>>(
        q_midb, q_b_wb, nullptr, qf, nullptr, nullptr, QRANK, NH*DQ, DQ);
    gemm_bf16<3><<<dim3(NH*256/128, NTOK/128), blk, 0, stream>>>(
        kv_lnb, kv_b_wb, nullptr, kf, Vtg, nullptr, KVRANK, NH*256, 0);

    // rope (kv_a part of amid has row stride 3072, k_pe at col 1536+512)
    rope_q_k<<<dim3(NBATCH*NH*SEQ*32/256), blk, 0, stream>>>(qf);
    rope_k_k<<<dim3(NBATCH*NH*SEQ*32/256), blk, 0, stream>>>(amid + QRANK, 3072, kf);

    // main attention
    float scale_main = 1.0f / sqrtf((float)DQ);
    flash_mfma<DQ><<<dim3(SEQ/64, NH, NBATCH), blk, 0, stream>>>(
        qf, kf, Vtg, ctx, scale_main);
    gemm_bf16<0><<<dim3(HIDN/128, NTOK/128), blk, 0, stream>>>(
        ctx, o_wb, out, nullptr, nullptr, nullptr, HIDN, HIDN, 0);  // main -> d_out

    // pattern branch: fused sp_q/k/v GEMM (M = 6144)
    gemm_bf16<4><<<dim3(3*HIDN/128, NTOK/128), blk, 0, stream>>>(
        Xb, spqkv_wb, nullptr, pq, pk, pvt, HIDN, 3*HIDN, 128);
    float scale_pat = 1.0f / sqrtf(128.0f);
    flash_mfma<128><<<dim3(SEQ/64, NH, NBATCH), blk, 0, stream>>>(
        pq, pk, pvt, p_ctx, scale_pat);
    gemm_bf16<0><<<dim3(HIDN/128, NTOK/128), blk, 0, stream>>>(
        p_ctx, sp_o_wb, patout, nullptr, nullptr, nullptr, HIDN, HIDN, 0);

    // gate + combine (reads d_out as main_out, overwrites d_out)
    gate_combine<<<dim3(NTOK), blk, 0, stream>>>(X, gate_w, gate_b, out, patout, out);
}